// Round 5
// baseline (227.574 us; speedup 1.0000x reference)
//
#include <hip/hip_runtime.h>

// DIM=16, K=8 -> N=256, BATCH=256. U = kron(I2 (x) Ufx, I2 (x) Ufy).
// Row index (ah,al,bh,bl), col index (ch,cl,dh,dl). ah,bh,ch,dh inert.
// Block = (bat, ah, bh, ch) and processes BOTH dh sub-tiles (they share cache
// lines): thread (al,bl,cl) loads 16 contiguous floats (dh=0 run + dh=1 run),
// stages dh0 in LDS, holds dh1 in registers, computes dh0, re-stages, computes dh1.
// Each 64x64 tile: four 8x8 complex contractions
//   P1: al <- Ufx, P2: bl <- Ufy, P3: cl <- conj Ufx, P4: dl <- conj Ufy (fused w/ store).
// LDS layout: L(al,bl,cl,dl) = al*512 + bl*64 + (cl^bl)*8 + (dl^cl)
// -> conflict-free (measured 0) for all passes; taps at base ^ {512k,72k,9k,k}.

__device__ float2 g_umat[256];  // [0,64) Ufx | [64,128) Ufy | [128,192) conj Ufx | [192,256) conj Ufy

__global__ void build_u_kernel(const float* __restrict__ phi_x,
                               const float* __restrict__ phi_y) {
    const int tid = threadIdx.x;
    if (tid >= 16) return;
    const float* phi = (tid < 8) ? phi_x : phi_y;
    const int c = tid & 7;
    float ur[8], ui[8];
#pragma unroll
    for (int r = 0; r < 8; ++r) { ur[r] = (r == c) ? 1.0f : 0.0f; ui[r] = 0.0f; }
    int p = 0;
#pragma unroll
    for (int layer = 0; layer < 8; ++layer) {
#pragma unroll
        for (int j = (layer & 1); j + 1 < 8; j += 2) {
            float sa, ca, sb, cb;
            sincosf(phi[p], &sa, &ca);
            sincosf(phi[p + 1], &sb, &cb);
            p += 2;
            // M = BS @ PS(phi_b) @ BS @ PS(phi_a)
            //   = 1/2 [[ea(eb-1), i(eb+1)], [i*ea*(eb+1), (1-eb)]]
            const float ear = ca, eai = sa, ebr = cb, ebi = sb;
            const float t1r = ebr - 1.0f, t1i = ebi;
            const float t2r = ebr + 1.0f, t2i = ebi;
            const float m00r = 0.5f * (ear * t1r - eai * t1i);
            const float m00i = 0.5f * (ear * t1i + eai * t1r);
            const float m01r = -0.5f * t2i;
            const float m01i = 0.5f * t2r;
            const float e2r = ear * t2r - eai * t2i;
            const float e2i = ear * t2i + eai * t2r;
            const float m10r = -0.5f * e2i;
            const float m10i = 0.5f * e2r;
            const float m11r = 0.5f * (1.0f - ebr);
            const float m11i = -0.5f * ebi;
            const float u0r = ur[j], u0i = ui[j], u1r = ur[j + 1], u1i = ui[j + 1];
            ur[j]     = m00r * u0r - m00i * u0i + m01r * u1r - m01i * u1i;
            ui[j]     = m00r * u0i + m00i * u0r + m01r * u1i + m01i * u1r;
            ur[j + 1] = m10r * u0r - m10i * u0i + m11r * u1r - m11i * u1i;
            ui[j + 1] = m10r * u0i + m10i * u0r + m11r * u1i + m11i * u1r;
        }
    }
    float2* Um = g_umat + ((tid < 8) ? 0 : 64);
    float2* Uc = g_umat + ((tid < 8) ? 128 : 192);
#pragma unroll
    for (int r = 0; r < 8; ++r) {
        Um[r * 8 + c] = make_float2(ur[r], ui[r]);
        Uc[r * 8 + c] = make_float2(ur[r], -ui[r]);
    }
}

// In-place 8-tap complex contraction on one fiber.
__device__ __forceinline__ void xpass(float2* __restrict__ sm,
                                      const float2* __restrict__ M,
                                      const int* idx) {
    float xr[8], xi[8];
#pragma unroll
    for (int k = 0; k < 8; ++k) {
        const float2 v = sm[idx[k]];
        xr[k] = v.x; xi[k] = v.y;
    }
#pragma unroll
    for (int o = 0; o < 8; ++o) {
        float ar = 0.0f, ai = 0.0f;
#pragma unroll
        for (int k = 0; k < 8; ++k) {
            const float2 m = M[o * 8 + k];   // wave-uniform -> scalar loads
            ar = fmaf(m.x, xr[k], ar); ar = fmaf(-m.y, xi[k], ar);
            ai = fmaf(m.x, xi[k], ai); ai = fmaf(m.y, xr[k], ai);
        }
        sm[idx[o]] = make_float2(ar, ai);
    }
}

__device__ __forceinline__ void stage_tile(float2* __restrict__ sm, int base,
                                           const float4& a0, const float4& a1,
                                           const float4& b0, const float4& b1) {
    sm[base ^ 0] = make_float2(a0.x, b0.x);
    sm[base ^ 1] = make_float2(a0.y, b0.y);
    sm[base ^ 2] = make_float2(a0.z, b0.z);
    sm[base ^ 3] = make_float2(a0.w, b0.w);
    sm[base ^ 4] = make_float2(a1.x, b1.x);
    sm[base ^ 5] = make_float2(a1.y, b1.y);
    sm[base ^ 6] = make_float2(a1.z, b1.z);
    sm[base ^ 7] = make_float2(a1.w, b1.w);
}

// P1..P3 in LDS, P4 fused with global store of this thread's 8-col dl-run.
template<bool CPLX>
__device__ __forceinline__ void compute_tile(float2* __restrict__ sm, int t,
                                             float* __restrict__ outF, size_t go) {
    // P1: contract al with Ufx. Taps at base + 512k.
    {
        const int bl = t >> 6, cl = (t >> 3) & 7, dl = t & 7;
        const int base = bl * 64 + ((cl ^ bl) << 3) + (dl ^ cl);
        int idx[8];
#pragma unroll
        for (int k = 0; k < 8; ++k) idx[k] = base + (k << 9);
        xpass(sm, g_umat + 0, idx);
    }
    __syncthreads();
    // P2: contract bl with Ufy. Taps at base ^ 72k.
    {
        const int al = t >> 6, cl = (t >> 3) & 7, dl = t & 7;
        const int base = al * 512 + (cl << 3) + (dl ^ cl);
        int idx[8];
#pragma unroll
        for (int k = 0; k < 8; ++k) idx[k] = base ^ (72 * k);
        xpass(sm, g_umat + 64, idx);
    }
    __syncthreads();
    // P3: contract cl with conj Ufx. Taps at base ^ 9k.
    {
        const int al = t >> 6, bl = (t >> 3) & 7, dl = t & 7;
        const int base = al * 512 + bl * 64 + (bl << 3) + dl;
        int idx[8];
#pragma unroll
        for (int k = 0; k < 8; ++k) idx[k] = base ^ (9 * k);
        xpass(sm, g_umat + 128, idx);
    }
    __syncthreads();
    // P4: contract dl with conj Ufy, fused with store.
    {
        const int al = t >> 6, bl = (t >> 3) & 7, cl = t & 7;
        const int base = al * 512 + bl * 64 + ((cl ^ bl) << 3) + cl;
        float xr[8], xi[8];
#pragma unroll
        for (int k = 0; k < 8; ++k) {
            const float2 v = sm[base ^ k];
            xr[k] = v.x; xi[k] = v.y;
        }
        const float2* __restrict__ M = g_umat + 192;
        if (!CPLX) {
            float o0[8];
#pragma unroll
            for (int o = 0; o < 8; ++o) {
                float ar = 0.0f;
#pragma unroll
                for (int k = 0; k < 8; ++k) {
                    const float2 m = M[o * 8 + k];
                    ar = fmaf(m.x, xr[k], ar);
                    ar = fmaf(-m.y, xi[k], ar);
                }
                o0[o] = ar;
            }
            *(float4*)(outF + go)     = make_float4(o0[0], o0[1], o0[2], o0[3]);
            *(float4*)(outF + go + 4) = make_float4(o0[4], o0[5], o0[6], o0[7]);
        } else {
            float2* dst = (float2*)outF + go;
#pragma unroll
            for (int o = 0; o < 8; ++o) {
                float ar = 0.0f, ai = 0.0f;
#pragma unroll
                for (int k = 0; k < 8; ++k) {
                    const float2 m = M[o * 8 + k];
                    ar = fmaf(m.x, xr[k], ar); ar = fmaf(-m.y, xi[k], ar);
                    ai = fmaf(m.x, xi[k], ai); ai = fmaf(m.y, xr[k], ai);
                }
                dst[o] = make_float2(ar, ai);
            }
        }
    }
}

template<bool CPLX>
__global__ __launch_bounds__(512, 8) void qconv_main(
    const float* __restrict__ rr, const float* __restrict__ ri,
    float* __restrict__ outF) {
    __shared__ float2 sm[4096];              // 32 KB -> 4 blocks/CU
    const int t = threadIdx.x;
    const int bid = blockIdx.x;
    const int ch = bid & 1;
    const int bh = (bid >> 1) & 1;
    const int ah = (bid >> 2) & 1;
    const int bat = bid >> 3;
    const int row0 = ah * 128 + bh * 8;      // global row = row0 + al*16 + bl
    const size_t mb = (size_t)bat * 65536;

    const int al = t >> 6, bl = (t >> 3) & 7, cl = t & 7;
    const int gi = row0 + al * 16 + bl;
    // 16 contiguous floats: cols ch*128 + cl*16 + [0,16) = dh0 run ++ dh1 run
    const size_t go = mb + (size_t)gi * 256 + (size_t)(ch * 128 + cl * 16);

    const float4 r0 = *(const float4*)(rr + go);
    const float4 r1 = *(const float4*)(rr + go + 4);
    const float4 r2 = *(const float4*)(rr + go + 8);    // dh1, held in regs
    const float4 r3 = *(const float4*)(rr + go + 12);
    const float4 i0 = *(const float4*)(ri + go);
    const float4 i1 = *(const float4*)(ri + go + 4);
    const float4 i2 = *(const float4*)(ri + go + 8);    // dh1, held in regs
    const float4 i3 = *(const float4*)(ri + go + 12);

    const int base = al * 512 + bl * 64 + ((cl ^ bl) << 3) + cl;  // dl=0 slot

    // ---- tile dh=0
    stage_tile(sm, base, r0, r1, i0, i1);
    __syncthreads();
    compute_tile<CPLX>(sm, t, outF, go);
    __syncthreads();                         // all P4 reads of dh0 done

    // ---- tile dh=1 (data already in registers: zero global latency)
    stage_tile(sm, base, r2, r3, i2, i3);
    __syncthreads();
    compute_tile<CPLX>(sm, t, outF, go + 8);
}

extern "C" void kernel_launch(void* const* d_in, const int* in_sizes, int n_in,
                              void* d_out, int out_size, void* d_ws, size_t ws_size,
                              hipStream_t stream) {
    const float* rr = (const float*)d_in[0];
    const float* ri = (const float*)d_in[1];
    const float* px = (const float*)d_in[2];
    const float* py = (const float*)d_in[3];
    const int batch = in_sizes[0] / 65536;
    const long long total = (long long)batch * 65536;
    build_u_kernel<<<1, 64, 0, stream>>>(px, py);
    if ((long long)out_size >= 2 * total) {
        qconv_main<true><<<batch * 8, 512, 0, stream>>>(rr, ri, (float*)d_out);
    } else {
        qconv_main<false><<<batch * 8, 512, 0, stream>>>(rr, ri, (float*)d_out);
    }
}